// Round 5
// baseline (665.467 us; speedup 1.0000x reference)
//
#include <hip/hip_runtime.h>
#include <hip/hip_bf16.h>

// ConceptBottleneck fused kernel, MI355X (gfx950).
// B=8192, IN=768, C=64, H=64, E=16.  Inputs/outputs fp32; internal math bf16 MFMA.
// prep_all: one launch — LDS-tiled transposes of [K x 64] weights (z<5) plus
//           fp32->bf16 copies / small strided transposes (z==5).
// cb_fused_t: grid (B/128, C); block = 128-row batch tile x one concept.
//   Layer-1 K-loop computes POS and NEG banks together (shared x tile, 32 MFMA
//   per barrier-pair per wave) with register-prefetch double buffering.
//   NOTE __launch_bounds__(256,2): (256,3) made LLVM target 6 waves/EU (84 VGPR)
//   and spill accN/prefetch to scratch -> 1.35 GB of phantom HBM writes (R4).

#define B_   8192
#define IN_  768
#define C_   64
#define H_   64
#define E_   16
#define BM_  128

typedef __bf16 bf16x8 __attribute__((ext_vector_type(8)));
typedef float  f32x4  __attribute__((ext_vector_type(4)));

__device__ __forceinline__ f32x4 mfma16(bf16x8 a, bf16x8 b, f32x4 c) {
  return __builtin_amdgcn_mfma_f32_16x16x32_bf16(a, b, c, 0, 0, 0);
}

__device__ __forceinline__ bf16x8 cvt8(float4 a, float4 b) {
  bf16x8 r;
  r[0] = (__bf16)a.x; r[1] = (__bf16)a.y; r[2] = (__bf16)a.z; r[3] = (__bf16)a.w;
  r[4] = (__bf16)b.x; r[5] = (__bf16)b.y; r[6] = (__bf16)b.z; r[7] = (__bf16)b.w;
  return r;
}

__device__ __forceinline__ void zero_acc(f32x4 (&acc)[2][4]) {
  const f32x4 z = {0.f, 0.f, 0.f, 0.f};
#pragma unroll
  for (int mt = 0; mt < 2; ++mt)
#pragma unroll
    for (int nt = 0; nt < 4; ++nt) acc[mt][nt] = z;
}

// ============================ MAIN KERNEL ===================================
// LDS (47616 B -> 3 blocks/CU):
//  xs [128][72] : x tile during L1; aliased as hb (activations) afterwards
//  wt[2][64][72]: pos/neg W1 tiles during L1; wt[0] = stage for all later layers
//  xcb[128][40] : pos|neg embeddings (cols 0..15 pos, 16..31 neg)
struct __align__(16) SmemT {
  __bf16 xs[BM_ * 72];
  __bf16 wt[2][64 * 72];
  __bf16 xcb[BM_ * 40];
  float  conc[BM_];
};
static_assert(sizeof(SmemT) <= 49152, "LDS overflow");

// Epilogue: C/D frags (col=lane&15, row=quad*4+reg) + fp32 bias, relu -> hb (stride 72)
__device__ __forceinline__ void epi72(__bf16* __restrict__ hb, f32x4 (&acc)[2][4],
                                      const float* __restrict__ bias,
                                      int wave, int quad, int l16) {
#pragma unroll
  for (int nt = 0; nt < 4; ++nt) {
    const int col = nt * 16 + l16;
    const float bv = bias[col];
#pragma unroll
    for (int mt = 0; mt < 2; ++mt)
#pragma unroll
      for (int r = 0; r < 4; ++r) {
        int row = wave * 32 + mt * 16 + quad * 4 + r;
        hb[row * 72 + col] = (__bf16)fmaxf(acc[mt][nt][r] + bv, 0.f);
      }
  }
}

// [128,64] @ [64,64]: A=hb (stride 72), B=wt [n][k] (stride 72), K=64.
__device__ __forceinline__ void gemm64(const __bf16* __restrict__ hb,
                                       const __bf16* __restrict__ wt,
                                       f32x4 (&acc)[2][4], int wave, int quad, int l16) {
#pragma unroll
  for (int ks = 0; ks < 2; ++ks) {
    bf16x8 a[2], bb[4];
#pragma unroll
    for (int mt = 0; mt < 2; ++mt)
      a[mt] = *(const bf16x8*)(hb + (wave * 32 + mt * 16 + l16) * 72 + ks * 32 + quad * 8);
#pragma unroll
    for (int nt = 0; nt < 4; ++nt)
      bb[nt] = *(const bf16x8*)(wt + (nt * 16 + l16) * 72 + ks * 32 + quad * 8);
#pragma unroll
    for (int mt = 0; mt < 2; ++mt)
#pragma unroll
      for (int nt = 0; nt < 4; ++nt)
        acc[mt][nt] = mfma16(a[mt], bb[nt], acc[mt][nt]);
  }
}

// Stage [64][64] bf16 tile (row-major contiguous) into wt (stride 72). 2 b128/thread.
__device__ __forceinline__ void stage_w64(const __bf16* __restrict__ Wt,
                                          __bf16* __restrict__ wt, int tid) {
#pragma unroll
  for (int it = 0; it < 2; ++it) {
    int q = tid + it * 256;
    int n = q >> 3, i = q & 7;
    *(uint4*)&wt[n * 72 + i * 8] = *(const uint4*)(Wt + n * 64 + i * 8);
  }
}

// L2+L3 of one bank, starting from acc1 (layer-1 accumulators in registers).
__device__ __forceinline__ void bank_tail(SmemT& sm, f32x4 (&acc1)[2][4],
    const float* __restrict__ b1,
    const __bf16* __restrict__ W2t, const float* __restrict__ b2,
    const __bf16* __restrict__ W3t, const float* __restrict__ b3,
    int xc_off, int tid, int wave, int quad, int l16)
{
  __bf16* hb  = sm.xs;
  __bf16* wt0 = sm.wt[0];

  epi72(hb, acc1, b1, wave, quad, l16);
  stage_w64(W2t, wt0, tid);
  __syncthreads();

  f32x4 acc2[2][4]; zero_acc(acc2);
  gemm64(hb, wt0, acc2, wave, quad, l16);
  __syncthreads();
  epi72(hb, acc2, b2, wave, quad, l16);
  if (tid < 128)
    *(uint4*)&wt0[(tid >> 3) * 72 + (tid & 7) * 8] =
        *(const uint4*)(W3t + (tid >> 3) * 64 + (tid & 7) * 8);
  __syncthreads();

  f32x4 acc3[2];
  { const f32x4 z = {0.f, 0.f, 0.f, 0.f}; acc3[0] = z; acc3[1] = z; }
#pragma unroll
  for (int ks = 0; ks < 2; ++ks) {
    bf16x8 bb = *(const bf16x8*)&wt0[l16 * 72 + ks * 32 + quad * 8];
#pragma unroll
    for (int mt = 0; mt < 2; ++mt) {
      bf16x8 a = *(const bf16x8*)&hb[(wave * 32 + mt * 16 + l16) * 72 + ks * 32 + quad * 8];
      acc3[mt] = mfma16(a, bb, acc3[mt]);
    }
  }
  {
    float bv = b3[l16];
#pragma unroll
    for (int mt = 0; mt < 2; ++mt)
#pragma unroll
      for (int r = 0; r < 4; ++r) {
        int row = wave * 32 + mt * 16 + quad * 4 + r;
        sm.xcb[row * 40 + xc_off + l16] = (__bf16)(acc3[mt][r] + bv);
      }
  }
  __syncthreads();
}

__global__ __launch_bounds__(256, 2) void cb_fused_t(
    const __bf16* __restrict__ x,
    const __bf16* __restrict__ pW1t, const float* __restrict__ pb1,
    const __bf16* __restrict__ pW2t, const float* __restrict__ pb2,
    const __bf16* __restrict__ pW3t, const float* __restrict__ pb3,
    const __bf16* __restrict__ nW1t, const float* __restrict__ nb1,
    const __bf16* __restrict__ nW2t, const float* __restrict__ nb2,
    const __bf16* __restrict__ nW3t, const float* __restrict__ nb3,
    const __bf16* __restrict__ cW1t, const float* __restrict__ cb1,
    const __bf16* __restrict__ cW2t, const float* __restrict__ cb2,
    const __bf16* __restrict__ cw3,  const float* __restrict__ cb3,
    float* __restrict__ out_emb, float* __restrict__ out_con)
{
  __shared__ SmemT sm;
  const int tid  = threadIdx.x;
  const int wave = tid >> 6, lane = tid & 63;
  const int quad = lane >> 4, l16 = lane & 15;
  const int row0 = blockIdx.x * BM_;
  const int c    = blockIdx.y;
  __bf16* hb  = sm.xs;
  __bf16* wt0 = sm.wt[0];

  const __bf16* W1p = pW1t + (size_t)c * 64 * IN_;
  const __bf16* W1n = nW1t + (size_t)c * 64 * IN_;

  // ---------- layer 1 (pos+neg merged): [128,768] @ [768,64] x2, BK=64 ----------
  f32x4 accP[2][4], accN[2][4];
  zero_acc(accP); zero_acc(accN);
  const int sr = tid >> 3, si = tid & 7;
  const __bf16* xg = x + (size_t)row0 * IN_;
  uint4 xv[4], pv[2], nv[2];

#pragma unroll
  for (int it = 0; it < 4; ++it)
    xv[it] = *(const uint4*)(xg + (size_t)(sr + it * 32) * IN_ + si * 8);
#pragma unroll
  for (int it = 0; it < 2; ++it) {
    pv[it] = *(const uint4*)(W1p + (size_t)(sr + it * 32) * IN_ + si * 8);
    nv[it] = *(const uint4*)(W1n + (size_t)(sr + it * 32) * IN_ + si * 8);
  }

  for (int kt = 0; kt < IN_ / 64; ++kt) {
#pragma unroll
    for (int it = 0; it < 4; ++it)
      *(uint4*)&sm.xs[(sr + it * 32) * 72 + si * 8] = xv[it];
#pragma unroll
    for (int it = 0; it < 2; ++it) {
      *(uint4*)&sm.wt[0][(sr + it * 32) * 72 + si * 8] = pv[it];
      *(uint4*)&sm.wt[1][(sr + it * 32) * 72 + si * 8] = nv[it];
    }
    __syncthreads();
    if (kt + 1 < IN_ / 64) {                    // register prefetch of next tile
      int ko = (kt + 1) * 64;
#pragma unroll
      for (int it = 0; it < 4; ++it)
        xv[it] = *(const uint4*)(xg + (size_t)(sr + it * 32) * IN_ + ko + si * 8);
#pragma unroll
      for (int it = 0; it < 2; ++it) {
        pv[it] = *(const uint4*)(W1p + (size_t)(sr + it * 32) * IN_ + ko + si * 8);
        nv[it] = *(const uint4*)(W1n + (size_t)(sr + it * 32) * IN_ + ko + si * 8);
      }
    }
#pragma unroll
    for (int ks = 0; ks < 2; ++ks) {
      bf16x8 a[2], bp[4], bn[4];
#pragma unroll
      for (int mt = 0; mt < 2; ++mt)
        a[mt] = *(const bf16x8*)&sm.xs[(wave * 32 + mt * 16 + l16) * 72 + ks * 32 + quad * 8];
#pragma unroll
      for (int nt = 0; nt < 4; ++nt) {
        bp[nt] = *(const bf16x8*)&sm.wt[0][(nt * 16 + l16) * 72 + ks * 32 + quad * 8];
        bn[nt] = *(const bf16x8*)&sm.wt[1][(nt * 16 + l16) * 72 + ks * 32 + quad * 8];
      }
#pragma unroll
      for (int mt = 0; mt < 2; ++mt)
#pragma unroll
        for (int nt = 0; nt < 4; ++nt) {
          accP[mt][nt] = mfma16(a[mt], bp[nt], accP[mt][nt]);
          accN[mt][nt] = mfma16(a[mt], bn[nt], accN[mt][nt]);
        }
    }
    __syncthreads();
  }

  // ---------- pos tail, then neg tail (accN held in registers) ----------
  bank_tail(sm, accP, pb1 + c * 64, pW2t + (size_t)c * 64 * 64, pb2 + c * 64,
            pW3t + (size_t)c * 16 * 64, pb3 + c * 16, 0, tid, wave, quad, l16);
  bank_tail(sm, accN, nb1 + c * 64, nW2t + (size_t)c * 64 * 64, nb2 + c * 64,
            nW3t + (size_t)c * 16 * 64, nb3 + c * 16, 16, tid, wave, quad, l16);

  // ---- cp layer 1: [128,32] @ [32,64]; A = xcb (stride 40), B = cW1t [64][32] ----
  {
    int n = tid >> 2, i = tid & 3;
    *(uint4*)&wt0[n * 72 + i * 8] = *(const uint4*)(cW1t + ((size_t)c * 64 + n) * 32 + i * 8);
  }
  __syncthreads();
  f32x4 acc1[2][4]; zero_acc(acc1);
  {
    bf16x8 a[2], bb[4];
#pragma unroll
    for (int mt = 0; mt < 2; ++mt)
      a[mt] = *(const bf16x8*)&sm.xcb[(wave * 32 + mt * 16 + l16) * 40 + quad * 8];
#pragma unroll
    for (int nt = 0; nt < 4; ++nt)
      bb[nt] = *(const bf16x8*)&wt0[(nt * 16 + l16) * 72 + quad * 8];
#pragma unroll
    for (int mt = 0; mt < 2; ++mt)
#pragma unroll
      for (int nt = 0; nt < 4; ++nt)
        acc1[mt][nt] = mfma16(a[mt], bb[nt], acc1[mt][nt]);
  }
  __syncthreads();
  epi72(hb, acc1, cb1 + c * 64, wave, quad, l16);
  stage_w64(cW2t + (size_t)c * 64 * 64, wt0, tid);
  __syncthreads();

  // ---- cp layer 2 ----
  f32x4 acc2[2][4]; zero_acc(acc2);
  gemm64(hb, wt0, acc2, wave, quad, l16);
  __syncthreads();
  epi72(hb, acc2, cb2 + c * 64, wave, quad, l16);
  if (tid < 8) *(uint4*)&wt0[tid * 8] = *(const uint4*)(cw3 + (size_t)c * 64 + tid * 8);
  __syncthreads();

  // ---- cp layer 3 (N=1 via MFMA; B nonzero only in lane col 0) ----
  f32x4 acc3[2];
  { const f32x4 z = {0.f, 0.f, 0.f, 0.f}; acc3[0] = z; acc3[1] = z; }
#pragma unroll
  for (int ks = 0; ks < 2; ++ks) {
    bf16x8 bb = {};
    if (l16 == 0) bb = *(const bf16x8*)&wt0[ks * 32 + quad * 8];
#pragma unroll
    for (int mt = 0; mt < 2; ++mt) {
      bf16x8 a = *(const bf16x8*)&hb[(wave * 32 + mt * 16 + l16) * 72 + ks * 32 + quad * 8];
      acc3[mt] = mfma16(a, bb, acc3[mt]);
    }
  }
  if (l16 == 0) {
    float bv = cb3[c];
#pragma unroll
    for (int mt = 0; mt < 2; ++mt)
#pragma unroll
      for (int r = 0; r < 4; ++r)
        sm.conc[wave * 32 + mt * 16 + quad * 4 + r] = acc3[mt][r] + bv;
  }
  __syncthreads();

  // ---- gate + outputs (fp32) ----
  for (int ii = tid; ii < BM_ * E_; ii += 256) {
    int row = ii >> 4, e = ii & 15;
    float cv = sm.conc[row];
    float w  = fminf(fmaxf(cv * 0.5f + 0.5f, 0.f), 1.f);
    float pv2 = (float)sm.xcb[row * 40 + e];
    float nv2 = (float)sm.xcb[row * 40 + 16 + e];
    out_emb[(size_t)(row0 + row) * (E_ * C_) + e * C_ + c] = pv2 * w + nv2 * (1.f - w);
  }
  if (tid < 128) out_con[(size_t)(row0 + tid) * C_ + c] = sm.conc[tid];
}

// ------------- prep_all: one launch for all conversions -----------------------
// z in [0,5): LDS-tiled transpose of [C][K][64] fp32 -> [C][64][K] bf16.
// z == 5   : grid-strided fp32->bf16 copies + small strided transposes.
#define TSEG 5
#define PSEG 5
struct PrepAllArgs {
  const float* tsrc[TSEG];
  __bf16*      tdst[TSEG];
  int          ktiles[TSEG];   // K/64
  const float* psrc[PSEG];
  __bf16*      pdst[PSEG];
  int pstart[PSEG + 1];        // flat chunk-index starts
  int kdiv8[PSEG];
  int N[PSEG];                 // 1 = plain copy, else transpose inner stride
};

__global__ __launch_bounds__(256) void prep_all(PrepAllArgs a) {
  const int tid = threadIdx.x;
  if (blockIdx.z < TSEG) {
    const int t  = blockIdx.z;
    const int kt = blockIdx.x;
    if (kt >= a.ktiles[t]) return;
    const int c  = blockIdx.y;
    const int K  = a.ktiles[t] * 64;
    const float* src = a.tsrc[t] + (size_t)c * K * 64 + (size_t)kt * 64 * 64;
    __bf16*      dst = a.tdst[t] + (size_t)c * 64 * K + kt * 64;
    __shared__ __bf16 lt[64 * 72];
    const int r = tid >> 4, c4 = (tid & 15) * 4;
#pragma unroll
    for (int it = 0; it < 4; ++it) {
      int k = r + it * 16;
      float4 v = *(const float4*)(src + (size_t)k * 64 + c4);
      lt[(c4 + 0) * 72 + k] = (__bf16)v.x;
      lt[(c4 + 1) * 72 + k] = (__bf16)v.y;
      lt[(c4 + 2) * 72 + k] = (__bf16)v.z;
      lt[(c4 + 3) * 72 + k] = (__bf16)v.w;
    }
    __syncthreads();
    const int n = tid >> 3, i = tid & 7;
#pragma unroll
    for (int it = 0; it < 2; ++it) {
      int nn = n + it * 32;
      *(uint4*)(dst + (size_t)nn * K + i * 8) = *(const uint4*)&lt[nn * 72 + i * 8];
    }
  } else {
    const int bid = blockIdx.x + gridDim.x * blockIdx.y;   // 0..(12*64-1)
    const int nth = gridDim.x * gridDim.y * 256;
    for (int idx = bid * 256 + tid; idx < a.pstart[PSEG]; idx += nth) {
      int seg = 0;
      while (seg < PSEG - 1 && idx >= a.pstart[seg + 1]) ++seg;
      int li = idx - a.pstart[seg];
      int kc = a.kdiv8[seg];
      int N  = a.N[seg];
      if (N == 1) {
        const float4* s = (const float4*)a.psrc[seg] + (size_t)li * 2;
        float4 v0 = s[0], v1 = s[1];
        *(uint4*)(a.pdst[seg] + (size_t)li * 8) = __builtin_bit_cast(uint4, cvt8(v0, v1));
      } else {
        int rn = li / kc;
        int k0 = (li - rn * kc) * 8;
        int cc = rn / N;
        int n  = rn - cc * N;
        const float* s = a.psrc[seg] + ((size_t)cc * kc * 8 + k0) * N + n;
        bf16x8 r;
#pragma unroll
        for (int j = 0; j < 8; ++j) r[j] = (__bf16)s[(size_t)j * N];
        *(uint4*)(a.pdst[seg] + (size_t)rn * kc * 8 + k0) = __builtin_bit_cast(uint4, r);
      }
    }
  }
}

// ============================== launch =======================================
extern "C" void kernel_launch(void* const* d_in, const int* in_sizes, int n_in,
                              void* d_out, int out_size, void* d_ws, size_t ws_size,
                              hipStream_t stream) {
  const float* xf   = (const float*)d_in[0];
  const float* pW1f = (const float*)d_in[1];
  const float* pb1f = (const float*)d_in[2];
  const float* pW2f = (const float*)d_in[3];
  const float* pb2f = (const float*)d_in[4];
  const float* pW3f = (const float*)d_in[5];
  const float* pb3f = (const float*)d_in[6];
  const float* nW1f = (const float*)d_in[7];
  const float* nb1f = (const float*)d_in[8];
  const float* nW2f = (const float*)d_in[9];
  const float* nb2f = (const float*)d_in[10];
  const float* nW3f = (const float*)d_in[11];
  const float* nb3f = (const float*)d_in[12];
  const float* cW1f = (const float*)d_in[13];
  const float* cb1f = (const float*)d_in[14];
  const float* cW2f = (const float*)d_in[15];
  const float* cb2f = (const float*)d_in[16];
  const float* cW3f = (const float*)d_in[17];
  const float* cb3f = (const float*)d_in[18];

  float* out_emb = (float*)d_out;
  float* out_con = out_emb + (size_t)B_ * E_ * C_;

  const int cx   = B_ * IN_;          // 6291456
  const int cW1c = C_ * IN_ * H_;     // 3145728
  const int cW2c = C_ * H_ * H_;      // 262144
  const int cW3c = C_ * H_ * E_;      // 65536
  const int ccW1 = C_ * 2 * E_ * H_;  // 131072
  const int ccW3 = C_ * H_;           // 4096

  __bf16* w = (__bf16*)d_ws;
  size_t o = 0;
  __bf16* xw   = w + o; o += cx;
  __bf16* pw1t = w + o; o += cW1c;
  __bf16* nw1t = w + o; o += cW1c;
  __bf16* pw2t = w + o; o += cW2c;
  __bf16* nw2t = w + o; o += cW2c;
  __bf16* cw2t = w + o; o += cW2c;
  __bf16* pw3t = w + o; o += cW3c;
  __bf16* nw3t = w + o; o += cW3c;
  __bf16* cw1t = w + o; o += ccW1;
  __bf16* cw3w = w + o; o += ccW3;

  PrepAllArgs a;
  {
    const float* tsrc[TSEG] = {pW1f, nW1f, pW2f, nW2f, cW2f};
    __bf16*      tdst[TSEG] = {pw1t, nw1t, pw2t, nw2t, cw2t};
    const int    tk[TSEG]   = {12,   12,   1,    1,    1};
    for (int i = 0; i < TSEG; ++i) { a.tsrc[i] = tsrc[i]; a.tdst[i] = tdst[i]; a.ktiles[i] = tk[i]; }

    const float* psrc[PSEG] = {xf, cW3f, pW3f, nW3f, cW1f};
    __bf16*      pdst[PSEG] = {xw, cw3w, pw3t, nw3t, cw1t};
    const int    pKs[PSEG]  = {0,  0,    64,   64,   32};
    const int    pNs[PSEG]  = {1,  1,    16,   16,   64};
    const int    pels[PSEG] = {cx, ccW3, cW3c, cW3c, ccW1};
    int s = 0;
    for (int i = 0; i < PSEG; ++i) {
      a.psrc[i] = psrc[i]; a.pdst[i] = pdst[i];
      a.kdiv8[i] = (pNs[i] == 1) ? (pels[i] / 8) : (pKs[i] / 8);
      a.N[i] = pNs[i];
      a.pstart[i] = s;
      s += pels[i] / 8;
    }
    a.pstart[PSEG] = s;
  }
  dim3 pgrid(12, C_, TSEG + 1);
  prep_all<<<pgrid, 256, 0, stream>>>(a);

  dim3 grid(B_ / BM_, C_);
  cb_fused_t<<<grid, 256, 0, stream>>>(xw,
      pw1t, pb1f, pw2t, pb2f, pw3t, pb3f,
      nw1t, nb1f, nw2t, nb2f, nw3t, nb3f,
      cw1t, cb1f, cw2t, cb2f, cw3w, cb3f,
      out_emb, out_con);
}

// Round 6
// 411.400 us; speedup vs baseline: 1.6176x; 1.6176x over previous
//
#include <hip/hip_runtime.h>
#include <hip/hip_bf16.h>

// ConceptBottleneck fused kernel, MI355X (gfx950).
// B=8192, IN=768, C=64, H=64, E=16.  Inputs/outputs fp32; internal math bf16 MFMA.
// prep_all: ONE flat-grid launch — LDS-tiled transposes of [K x 64] weights plus
//           fp32->bf16 copies / small strided transposes. No dead blocks.
// cb_fused_t: grid (B/128, C); block = 128-row batch tile x one concept.
//   Layer-1 K-loop computes POS and NEG banks together (shared x tile, 32 MFMA
//   per barrier-pair per wave).
//   SPILL SAGA: __launch_bounds__(256,3) -> LLVM targeted 6 waves/EU, 84 VGPR,
//   spilled accN/prefetch -> 1.35 GB phantom HBM writebacks (R4). (256,2) did
//   NOT help (R5: 80 VGPR, 1.6 GB): the 2nd arg only caps VGPRs, the scheduler
//   still CHASES its own occupancy target by spilling. amdgpu_waves_per_eu(2,3)
//   pins the target range; prefetch removed to cut live pressure further.

#define B_   8192
#define IN_  768
#define C_   64
#define H_   64
#define E_   16
#define BM_  128

typedef __bf16 bf16x8 __attribute__((ext_vector_type(8)));
typedef float  f32x4  __attribute__((ext_vector_type(4)));

__device__ __forceinline__ f32x4 mfma16(bf16x8 a, bf16x8 b, f32x4 c) {
  return __builtin_amdgcn_mfma_f32_16x16x32_bf16(a, b, c, 0, 0, 0);
}

__device__ __forceinline__ bf16x8 cvt8(float4 a, float4 b) {
  bf16x8 r;
  r[0] = (__bf16)a.x; r[1] = (__bf16)a.y; r[2] = (__bf16)a.z; r[3] = (__bf16)a.w;
  r[4] = (__bf16)b.x; r[5] = (__bf16)b.y; r[6] = (__bf16)b.z; r[7] = (__bf16)b.w;
  return r;
}

__device__ __forceinline__ void zero_acc(f32x4 (&acc)[2][4]) {
  const f32x4 z = {0.f, 0.f, 0.f, 0.f};
#pragma unroll
  for (int mt = 0; mt < 2; ++mt)
#pragma unroll
    for (int nt = 0; nt < 4; ++nt) acc[mt][nt] = z;
}

// ============================ MAIN KERNEL ===================================
// LDS (47616 B -> 3 blocks/CU):
//  xs [128][72] : x tile during L1; aliased as hb (activations) afterwards
//  wt[2][64][72]: pos/neg W1 tiles during L1; wt[0] = stage for all later layers
//  xcb[128][40] : pos|neg embeddings (cols 0..15 pos, 16..31 neg)
struct __align__(16) SmemT {
  __bf16 xs[BM_ * 72];
  __bf16 wt[2][64 * 72];
  __bf16 xcb[BM_ * 40];
  float  conc[BM_];
};
static_assert(sizeof(SmemT) <= 49152, "LDS overflow");

// Epilogue: C/D frags (col=lane&15, row=quad*4+reg) + fp32 bias, relu -> hb (stride 72)
__device__ __forceinline__ void epi72(__bf16* __restrict__ hb, f32x4 (&acc)[2][4],
                                      const float* __restrict__ bias,
                                      int wave, int quad, int l16) {
#pragma unroll
  for (int nt = 0; nt < 4; ++nt) {
    const int col = nt * 16 + l16;
    const float bv = bias[col];
#pragma unroll
    for (int mt = 0; mt < 2; ++mt)
#pragma unroll
      for (int r = 0; r < 4; ++r) {
        int row = wave * 32 + mt * 16 + quad * 4 + r;
        hb[row * 72 + col] = (__bf16)fmaxf(acc[mt][nt][r] + bv, 0.f);
      }
  }
}

// [128,64] @ [64,64]: A=hb (stride 72), B=wt [n][k] (stride 72), K=64.
__device__ __forceinline__ void gemm64(const __bf16* __restrict__ hb,
                                       const __bf16* __restrict__ wt,
                                       f32x4 (&acc)[2][4], int wave, int quad, int l16) {
#pragma unroll
  for (int ks = 0; ks < 2; ++ks) {
    bf16x8 a[2], bb[4];
#pragma unroll
    for (int mt = 0; mt < 2; ++mt)
      a[mt] = *(const bf16x8*)(hb + (wave * 32 + mt * 16 + l16) * 72 + ks * 32 + quad * 8);
#pragma unroll
    for (int nt = 0; nt < 4; ++nt)
      bb[nt] = *(const bf16x8*)(wt + (nt * 16 + l16) * 72 + ks * 32 + quad * 8);
#pragma unroll
    for (int mt = 0; mt < 2; ++mt)
#pragma unroll
      for (int nt = 0; nt < 4; ++nt)
        acc[mt][nt] = mfma16(a[mt], bb[nt], acc[mt][nt]);
  }
}

// Stage [64][64] bf16 tile (row-major contiguous) into wt (stride 72). 2 b128/thread.
__device__ __forceinline__ void stage_w64(const __bf16* __restrict__ Wt,
                                          __bf16* __restrict__ wt, int tid) {
#pragma unroll
  for (int it = 0; it < 2; ++it) {
    int q = tid + it * 256;
    int n = q >> 3, i = q & 7;
    *(uint4*)&wt[n * 72 + i * 8] = *(const uint4*)(Wt + n * 64 + i * 8);
  }
}

// L2+L3 of one bank, starting from acc1 (layer-1 accumulators in registers).
__device__ __forceinline__ void bank_tail(SmemT& sm, f32x4 (&acc1)[2][4],
    const float* __restrict__ b1,
    const __bf16* __restrict__ W2t, const float* __restrict__ b2,
    const __bf16* __restrict__ W3t, const float* __restrict__ b3,
    int xc_off, int tid, int wave, int quad, int l16)
{
  __bf16* hb  = sm.xs;
  __bf16* wt0 = sm.wt[0];

  epi72(hb, acc1, b1, wave, quad, l16);
  stage_w64(W2t, wt0, tid);
  __syncthreads();

  f32x4 acc2[2][4]; zero_acc(acc2);
  gemm64(hb, wt0, acc2, wave, quad, l16);
  __syncthreads();
  epi72(hb, acc2, b2, wave, quad, l16);
  if (tid < 128)
    *(uint4*)&wt0[(tid >> 3) * 72 + (tid & 7) * 8] =
        *(const uint4*)(W3t + (tid >> 3) * 64 + (tid & 7) * 8);
  __syncthreads();

  f32x4 acc3[2];
  { const f32x4 z = {0.f, 0.f, 0.f, 0.f}; acc3[0] = z; acc3[1] = z; }
#pragma unroll
  for (int ks = 0; ks < 2; ++ks) {
    bf16x8 bb = *(const bf16x8*)&wt0[l16 * 72 + ks * 32 + quad * 8];
#pragma unroll
    for (int mt = 0; mt < 2; ++mt) {
      bf16x8 a = *(const bf16x8*)&hb[(wave * 32 + mt * 16 + l16) * 72 + ks * 32 + quad * 8];
      acc3[mt] = mfma16(a, bb, acc3[mt]);
    }
  }
  {
    float bv = b3[l16];
#pragma unroll
    for (int mt = 0; mt < 2; ++mt)
#pragma unroll
      for (int r = 0; r < 4; ++r) {
        int row = wave * 32 + mt * 16 + quad * 4 + r;
        sm.xcb[row * 40 + xc_off + l16] = (__bf16)(acc3[mt][r] + bv);
      }
  }
  __syncthreads();
}

__global__ __launch_bounds__(256)
__attribute__((amdgpu_waves_per_eu(2, 3)))
void cb_fused_t(
    const __bf16* __restrict__ x,
    const __bf16* __restrict__ pW1t, const float* __restrict__ pb1,
    const __bf16* __restrict__ pW2t, const float* __restrict__ pb2,
    const __bf16* __restrict__ pW3t, const float* __restrict__ pb3,
    const __bf16* __restrict__ nW1t, const float* __restrict__ nb1,
    const __bf16* __restrict__ nW2t, const float* __restrict__ nb2,
    const __bf16* __restrict__ nW3t, const float* __restrict__ nb3,
    const __bf16* __restrict__ cW1t, const float* __restrict__ cb1,
    const __bf16* __restrict__ cW2t, const float* __restrict__ cb2,
    const __bf16* __restrict__ cw3,  const float* __restrict__ cb3,
    float* __restrict__ out_emb, float* __restrict__ out_con)
{
  __shared__ SmemT sm;
  const int tid  = threadIdx.x;
  const int wave = tid >> 6, lane = tid & 63;
  const int quad = lane >> 4, l16 = lane & 15;
  const int row0 = blockIdx.x * BM_;
  const int c    = blockIdx.y;
  __bf16* hb  = sm.xs;
  __bf16* wt0 = sm.wt[0];

  const __bf16* W1p = pW1t + (size_t)c * 64 * IN_;
  const __bf16* W1n = nW1t + (size_t)c * 64 * IN_;

  // ---------- layer 1 (pos+neg merged): [128,768] @ [768,64] x2, BK=64 ----------
  f32x4 accP[2][4], accN[2][4];
  zero_acc(accP); zero_acc(accN);
  const int sr = tid >> 3, si = tid & 7;
  const __bf16* xg = x + (size_t)row0 * IN_;

  for (int kt = 0; kt < IN_ / 64; ++kt) {
    const int ko = kt * 64;
    uint4 xv[4], pv[2], nv[2];
#pragma unroll
    for (int it = 0; it < 4; ++it)
      xv[it] = *(const uint4*)(xg + (size_t)(sr + it * 32) * IN_ + ko + si * 8);
#pragma unroll
    for (int it = 0; it < 2; ++it) {
      pv[it] = *(const uint4*)(W1p + (size_t)(sr + it * 32) * IN_ + ko + si * 8);
      nv[it] = *(const uint4*)(W1n + (size_t)(sr + it * 32) * IN_ + ko + si * 8);
    }
#pragma unroll
    for (int it = 0; it < 4; ++it)
      *(uint4*)&sm.xs[(sr + it * 32) * 72 + si * 8] = xv[it];
#pragma unroll
    for (int it = 0; it < 2; ++it) {
      *(uint4*)&sm.wt[0][(sr + it * 32) * 72 + si * 8] = pv[it];
      *(uint4*)&sm.wt[1][(sr + it * 32) * 72 + si * 8] = nv[it];
    }
    __syncthreads();
#pragma unroll
    for (int ks = 0; ks < 2; ++ks) {
      bf16x8 a[2], bp[4], bn[4];
#pragma unroll
      for (int mt = 0; mt < 2; ++mt)
        a[mt] = *(const bf16x8*)&sm.xs[(wave * 32 + mt * 16 + l16) * 72 + ks * 32 + quad * 8];
#pragma unroll
      for (int nt = 0; nt < 4; ++nt) {
        bp[nt] = *(const bf16x8*)&sm.wt[0][(nt * 16 + l16) * 72 + ks * 32 + quad * 8];
        bn[nt] = *(const bf16x8*)&sm.wt[1][(nt * 16 + l16) * 72 + ks * 32 + quad * 8];
      }
#pragma unroll
      for (int mt = 0; mt < 2; ++mt)
#pragma unroll
        for (int nt = 0; nt < 4; ++nt) {
          accP[mt][nt] = mfma16(a[mt], bp[nt], accP[mt][nt]);
          accN[mt][nt] = mfma16(a[mt], bn[nt], accN[mt][nt]);
        }
    }
    __syncthreads();
  }

  // ---------- pos tail, then neg tail (accN held in registers) ----------
  bank_tail(sm, accP, pb1 + c * 64, pW2t + (size_t)c * 64 * 64, pb2 + c * 64,
            pW3t + (size_t)c * 16 * 64, pb3 + c * 16, 0, tid, wave, quad, l16);
  bank_tail(sm, accN, nb1 + c * 64, nW2t + (size_t)c * 64 * 64, nb2 + c * 64,
            nW3t + (size_t)c * 16 * 64, nb3 + c * 16, 16, tid, wave, quad, l16);

  // ---- cp layer 1: [128,32] @ [32,64]; A = xcb (stride 40), B = cW1t [64][32] ----
  {
    int n = tid >> 2, i = tid & 3;
    *(uint4*)&wt0[n * 72 + i * 8] = *(const uint4*)(cW1t + ((size_t)c * 64 + n) * 32 + i * 8);
  }
  __syncthreads();
  f32x4 acc1[2][4]; zero_acc(acc1);
  {
    bf16x8 a[2], bb[4];
#pragma unroll
    for (int mt = 0; mt < 2; ++mt)
      a[mt] = *(const bf16x8*)&sm.xcb[(wave * 32 + mt * 16 + l16) * 40 + quad * 8];
#pragma unroll
    for (int nt = 0; nt < 4; ++nt)
      bb[nt] = *(const bf16x8*)&wt0[(nt * 16 + l16) * 72 + quad * 8];
#pragma unroll
    for (int mt = 0; mt < 2; ++mt)
#pragma unroll
      for (int nt = 0; nt < 4; ++nt)
        acc1[mt][nt] = mfma16(a[mt], bb[nt], acc1[mt][nt]);
  }
  __syncthreads();
  epi72(hb, acc1, cb1 + c * 64, wave, quad, l16);
  stage_w64(cW2t + (size_t)c * 64 * 64, wt0, tid);
  __syncthreads();

  // ---- cp layer 2 ----
  f32x4 acc2[2][4]; zero_acc(acc2);
  gemm64(hb, wt0, acc2, wave, quad, l16);
  __syncthreads();
  epi72(hb, acc2, cb2 + c * 64, wave, quad, l16);
  if (tid < 8) *(uint4*)&wt0[tid * 8] = *(const uint4*)(cw3 + (size_t)c * 64 + tid * 8);
  __syncthreads();

  // ---- cp layer 3 (N=1 via MFMA; B nonzero only in lane col 0) ----
  f32x4 acc3[2];
  { const f32x4 z = {0.f, 0.f, 0.f, 0.f}; acc3[0] = z; acc3[1] = z; }
#pragma unroll
  for (int ks = 0; ks < 2; ++ks) {
    bf16x8 bb = {};
    if (l16 == 0) bb = *(const bf16x8*)&wt0[ks * 32 + quad * 8];
#pragma unroll
    for (int mt = 0; mt < 2; ++mt) {
      bf16x8 a = *(const bf16x8*)&hb[(wave * 32 + mt * 16 + l16) * 72 + ks * 32 + quad * 8];
      acc3[mt] = mfma16(a, bb, acc3[mt]);
    }
  }
  if (l16 == 0) {
    float bv = cb3[c];
#pragma unroll
    for (int mt = 0; mt < 2; ++mt)
#pragma unroll
      for (int r = 0; r < 4; ++r)
        sm.conc[wave * 32 + mt * 16 + quad * 4 + r] = acc3[mt][r] + bv;
  }
  __syncthreads();

  // ---- gate + outputs (fp32) ----
  for (int ii = tid; ii < BM_ * E_; ii += 256) {
    int row = ii >> 4, e = ii & 15;
    float cv = sm.conc[row];
    float w  = fminf(fmaxf(cv * 0.5f + 0.5f, 0.f), 1.f);
    float pv2 = (float)sm.xcb[row * 40 + e];
    float nv2 = (float)sm.xcb[row * 40 + 16 + e];
    out_emb[(size_t)(row0 + row) * (E_ * C_) + e * C_ + c] = pv2 * w + nv2 * (1.f - w);
  }
  if (tid < 128) out_con[(size_t)(row0 + tid) * C_ + c] = sm.conc[tid];
}

// ------------- prep_all: ONE flat 1D launch, no dead blocks -------------------
// Blocks [0, tblocks): LDS-tiled transpose of [C][K][64] fp32 -> [C][64][K] bf16,
//   one (c, kt) 64x64 tile per block.
// Blocks [tblocks, ...): fp32->bf16 copies (N==1) / small strided transposes,
//   256 chunks of 8 elems per block (all segment sizes are exact multiples).
#define TSEG 5
#define PSEG 5
struct PrepArgs {
  const float* tsrc[TSEG];
  __bf16*      tdst[TSEG];
  int tstart[TSEG + 1];
  int ktiles[TSEG];            // K/64
  const float* psrc[PSEG];
  __bf16*      pdst[PSEG];
  int pstart[PSEG + 1];        // block starts (after tblocks)
  int kdiv8[PSEG];
  int N[PSEG];                 // 1 = plain copy, else transpose inner stride
  int tblocks;
};

__global__ __launch_bounds__(256) void prep_all(PrepArgs a) {
  const int tid = threadIdx.x;
  const int b = blockIdx.x;
  __shared__ __bf16 lt[64 * 72];
  if (b < a.tblocks) {
    int s = 0;
    while (s < TSEG - 1 && b >= a.tstart[s + 1]) ++s;
    const int idx = b - a.tstart[s];
    const int kt = idx % a.ktiles[s];
    const int c  = idx / a.ktiles[s];
    const int K  = a.ktiles[s] * 64;
    const float* src = a.tsrc[s] + (size_t)c * K * 64 + (size_t)kt * 64 * 64;
    __bf16*      dst = a.tdst[s] + (size_t)c * 64 * K + kt * 64;
    const int r = tid >> 4, c4 = (tid & 15) * 4;
#pragma unroll
    for (int it = 0; it < 4; ++it) {
      int k = r + it * 16;
      float4 v = *(const float4*)(src + (size_t)k * 64 + c4);
      lt[(c4 + 0) * 72 + k] = (__bf16)v.x;
      lt[(c4 + 1) * 72 + k] = (__bf16)v.y;
      lt[(c4 + 2) * 72 + k] = (__bf16)v.z;
      lt[(c4 + 3) * 72 + k] = (__bf16)v.w;
    }
    __syncthreads();
    const int n = tid >> 3, i = tid & 7;
#pragma unroll
    for (int it = 0; it < 2; ++it) {
      int nn = n + it * 32;
      *(uint4*)(dst + (size_t)nn * K + i * 8) = *(const uint4*)&lt[nn * 72 + i * 8];
    }
  } else {
    const int bb = b - a.tblocks;
    int s = 0;
    while (s < PSEG - 1 && bb >= a.pstart[s + 1]) ++s;
    const int li = (bb - a.pstart[s]) * 256 + tid;
    const int kc = a.kdiv8[s];
    const int N  = a.N[s];
    if (N == 1) {
      const float4* src = (const float4*)a.psrc[s] + (size_t)li * 2;
      float4 v0 = src[0], v1 = src[1];
      *(uint4*)(a.pdst[s] + (size_t)li * 8) = __builtin_bit_cast(uint4, cvt8(v0, v1));
    } else {
      int rn = li / kc;
      int k0 = (li - rn * kc) * 8;
      int cc = rn / N;
      int n  = rn - cc * N;
      const float* src = a.psrc[s] + ((size_t)cc * kc * 8 + k0) * N + n;
      bf16x8 r;
#pragma unroll
      for (int j = 0; j < 8; ++j) r[j] = (__bf16)src[(size_t)j * N];
      *(uint4*)(a.pdst[s] + (size_t)rn * kc * 8 + k0) = __builtin_bit_cast(uint4, r);
    }
  }
}

// ============================== launch =======================================
extern "C" void kernel_launch(void* const* d_in, const int* in_sizes, int n_in,
                              void* d_out, int out_size, void* d_ws, size_t ws_size,
                              hipStream_t stream) {
  const float* xf   = (const float*)d_in[0];
  const float* pW1f = (const float*)d_in[1];
  const float* pb1f = (const float*)d_in[2];
  const float* pW2f = (const float*)d_in[3];
  const float* pb2f = (const float*)d_in[4];
  const float* pW3f = (const float*)d_in[5];
  const float* pb3f = (const float*)d_in[6];
  const float* nW1f = (const float*)d_in[7];
  const float* nb1f = (const float*)d_in[8];
  const float* nW2f = (const float*)d_in[9];
  const float* nb2f = (const float*)d_in[10];
  const float* nW3f = (const float*)d_in[11];
  const float* nb3f = (const float*)d_in[12];
  const float* cW1f = (const float*)d_in[13];
  const float* cb1f = (const float*)d_in[14];
  const float* cW2f = (const float*)d_in[15];
  const float* cb2f = (const float*)d_in[16];
  const float* cW3f = (const float*)d_in[17];
  const float* cb3f = (const float*)d_in[18];

  float* out_emb = (float*)d_out;
  float* out_con = out_emb + (size_t)B_ * E_ * C_;

  const int cx   = B_ * IN_;          // 6291456
  const int cW1c = C_ * IN_ * H_;     // 3145728
  const int cW2c = C_ * H_ * H_;      // 262144
  const int cW3c = C_ * H_ * E_;      // 65536
  const int ccW1 = C_ * 2 * E_ * H_;  // 131072
  const int ccW3 = C_ * H_;           // 4096

  __bf16* w = (__bf16*)d_ws;
  size_t o = 0;
  __bf16* xw   = w + o; o += cx;
  __bf16* pw1t = w + o; o += cW1c;
  __bf16* nw1t = w + o; o += cW1c;
  __bf16* pw2t = w + o; o += cW2c;
  __bf16* nw2t = w + o; o += cW2c;
  __bf16* cw2t = w + o; o += cW2c;
  __bf16* pw3t = w + o; o += cW3c;
  __bf16* nw3t = w + o; o += cW3c;
  __bf16* cw1t = w + o; o += ccW1;
  __bf16* cw3w = w + o; o += ccW3;

  PrepArgs a;
  int tb = 0, pb = 0;
  {
    const float* tsrc[TSEG] = {pW1f, nW1f, pW2f, nW2f, cW2f};
    __bf16*      tdst[TSEG] = {pw1t, nw1t, pw2t, nw2t, cw2t};
    const int    tk[TSEG]   = {12,   12,   1,    1,    1};
    for (int i = 0; i < TSEG; ++i) {
      a.tsrc[i] = tsrc[i]; a.tdst[i] = tdst[i]; a.ktiles[i] = tk[i];
      a.tstart[i] = tb;
      tb += tk[i] * C_;
    }
    a.tstart[TSEG] = tb;
    a.tblocks = tb;

    const float* psrc[PSEG] = {xf, cW3f, pW3f, nW3f, cW1f};
    __bf16*      pdst[PSEG] = {xw, cw3w, pw3t, nw3t, cw1t};
    const int    pKs[PSEG]  = {0,  0,    64,   64,   32};
    const int    pNs[PSEG]  = {1,  1,    16,   16,   64};
    const int    pels[PSEG] = {cx, ccW3, cW3c, cW3c, ccW1};
    for (int i = 0; i < PSEG; ++i) {
      a.psrc[i] = psrc[i]; a.pdst[i] = pdst[i];
      a.kdiv8[i] = (pNs[i] == 1) ? (pels[i] / 8) : (pKs[i] / 8);
      a.N[i] = pNs[i];
      a.pstart[i] = pb;
      pb += pels[i] / (8 * 256);     // all exact multiples of 2048 elems
    }
    a.pstart[PSEG] = pb;
  }
  prep_all<<<tb + pb, 256, 0, stream>>>(a);

  dim3 grid(B_ / BM_, C_);
  cb_fused_t<<<grid, 256, 0, stream>>>(xw,
      pw1t, pb1f, pw2t, pb2f, pw3t, pb3f,
      nw1t, nb1f, nw2t, nb2f, nw3t, nb3f,
      cw1t, cb1f, cw2t, cb2f, cw3w, cb3f,
      out_emb, out_con);
}